// Round 8
// baseline (341.415 us; speedup 1.0000x reference)
//
#include <hip/hip_runtime.h>

#define I_DIM 2304
#define J_DIM 32
#define D_IN  8
#define E_DIM 16
#define B_DIM 64
#define BJE   (B_DIM * J_DIM * E_DIM)  // 32768
#define NC8   256
#define CH8   (I_DIM / NC8)            // 9
#define TILEW 4096                     // floats per 16KB W tile

typedef const __attribute__((address_space(1))) char* gcp_t;
typedef __attribute__((address_space(3)))       char* lcp_t;

// grid = 256 (one block per i-chunk = one per CU), 512 threads = 8 waves.
// ALL 9 W tiles (144 KB) DMA'd to LDS once (source-XOR-swizzled, linear dest),
// then the pass runs with ZERO barriers: wave wv owns b = wv*8+bb (all 64 b
// covered), lane = (jj = j, eh = e-half); per lane 8 b x 8 e.
// x: 1 dword/lane/iteration -> wave-private LDS slot (wave-coherent, no
// barrier), double-buffered, prefetched one iteration ahead.
__global__ __launch_bounds__(512, 2) void caps_pass_v8(
    const float* __restrict__ x,    // [B, I, 8]
    const float* __restrict__ W,    // [I, J, 8, 16]
    const float* __restrict__ b0,   // [I, J]
    const float* __restrict__ Vacc, // [B, J, 16]
    float* __restrict__ partial)    // [NC8, B, J, 16]
{
    const int tid   = threadIdx.x;
    const int wv    = __builtin_amdgcn_readfirstlane(tid >> 6);  // 0..7 (SGPR)
    const int lane  = tid & 63;
    const int jj    = lane & 31;
    const int eh    = lane >> 5;
    const int km    = jj & 15;
    const int chunk = blockIdx.x;          // 0..255
    const int i0    = chunk * CH8;
    const int bw0   = wv * 8;              // wave's global b base

    __shared__ float Ws[CH8 * TILEW];      // 147,456 B
    __shared__ float Xw[8][2][64];         // 4,096 B  [wave][buf][d*8+bl]
    __shared__ float B0s[CH8 * J_DIM];     // 1,152 B

    // ---- prologue: DMA all 9 W tiles; stage b0; stage x(i0) ----
    for (int t = 0; t < CH8; ++t) {
        const char* wt = (const char*)(W + (size_t)(i0 + t) * TILEW);
#pragma unroll
        for (int r = 0; r < 2; ++r) {
            const int g    = (wv * 2 + r) * 64 + lane;                  // unit 0..1023
            const int srcu = (g & ~31) | ((g & 31) ^ ((g >> 5) & 15));  // swizzled src
            __builtin_amdgcn_global_load_lds(
                (gcp_t)(wt + (size_t)srcu * 16),
                (lcp_t)((char*)&Ws[t * TILEW + (wv * 2 + r) * 256]),
                16, 0, 0);
        }
    }
    if (tid < CH8 * J_DIM) B0s[tid] = b0[i0 * J_DIM + tid];
    {
        // lane -> (bl = lane>>3, d = lane&7); transposed slot layout [d*8+bl]
        const float xv0 = x[((size_t)(bw0 + (lane >> 3)) * I_DIM + i0) * D_IN + (lane & 7)];
        Xw[wv][0][(lane & 7) * 8 + (lane >> 3)] = xv0;
    }

    // vacc in regs (per-lane: 8 b x 8 e)
    float vacc[8][8];
#pragma unroll
    for (int bb = 0; bb < 8; ++bb) {
        const float* vp = Vacc + ((size_t)((bw0 + bb) * J_DIM + jj)) * E_DIM + eh * 8;
        const float4 v0 = *(const float4*)vp;
        const float4 v1 = *(const float4*)(vp + 4);
        vacc[bb][0]=v0.x; vacc[bb][1]=v0.y; vacc[bb][2]=v0.z; vacc[bb][3]=v0.w;
        vacc[bb][4]=v1.x; vacc[bb][5]=v1.y; vacc[bb][6]=v1.z; vacc[bb][7]=v1.w;
    }

    float Sacc[8][8];
#pragma unroll
    for (int bb = 0; bb < 8; ++bb)
#pragma unroll
        for (int e = 0; e < 8; ++e) Sacc[bb][e] = 0.f;

    __syncthreads();   // ONLY barrier: drains W-DMA + b0 + x(i0)

    for (int ii = 0; ii < CH8; ++ii) {
        // prefetch next x (1 dword/lane) — committed at iteration end
        float xnext = 0.f;
        if (ii + 1 < CH8)
            xnext = x[((size_t)(bw0 + (lane >> 3)) * I_DIM + (i0 + ii + 1)) * D_IN + (lane & 7)];

        const float* wb = &Ws[ii * TILEW];
        const float* xr = &Xw[wv][ii & 1][0];

        float uh[8][8];
#pragma unroll
        for (int bb = 0; bb < 8; ++bb)
#pragma unroll
            for (int e = 0; e < 8; ++e) uh[bb][e] = 0.f;

#pragma unroll
        for (int d = 0; d < D_IN; ++d) {
            const int u0 = (d << 2) | (eh << 1);
            const float4 wlo = *(const float4*)&wb[jj * 128 + (((u0    ) ^ km) << 2)];
            const float4 whi = *(const float4*)&wb[jj * 128 + (((u0 | 1) ^ km) << 2)];
            const float4 xa  = *(const float4*)&xr[d * 8];      // uniform broadcast
            const float4 xb4 = *(const float4*)&xr[d * 8 + 4];
            const float xq[8] = {xa.x, xa.y, xa.z, xa.w, xb4.x, xb4.y, xb4.z, xb4.w};
#pragma unroll
            for (int bb = 0; bb < 8; ++bb) {
                const float xv = xq[bb];
                uh[bb][0] = fmaf(xv, wlo.x, uh[bb][0]);
                uh[bb][1] = fmaf(xv, wlo.y, uh[bb][1]);
                uh[bb][2] = fmaf(xv, wlo.z, uh[bb][2]);
                uh[bb][3] = fmaf(xv, wlo.w, uh[bb][3]);
                uh[bb][4] = fmaf(xv, whi.x, uh[bb][4]);
                uh[bb][5] = fmaf(xv, whi.y, uh[bb][5]);
                uh[bb][6] = fmaf(xv, whi.z, uh[bb][6]);
                uh[bb][7] = fmaf(xv, whi.w, uh[bb][7]);
            }
        }

        const float b0v = B0s[ii * J_DIM + jj];
#pragma unroll
        for (int bb = 0; bb < 8; ++bb) {
            float l0 = 0.f, l1 = 0.f;
#pragma unroll
            for (int e = 0; e < 8; e += 2) {
                l0 = fmaf(vacc[bb][e],     uh[bb][e],     l0);
                l1 = fmaf(vacc[bb][e + 1], uh[bb][e + 1], l1);
            }
            float lg = l0 + l1;
            lg += __shfl_xor(lg, 32);              // other e-half
            const float l = b0v + lg;

            // softmax over jj (no max-sub: |l| fp32-safe; exact-math equal)
            const float p = __expf(l);
            float s = p;
#pragma unroll
            for (int k = 16; k >= 1; k >>= 1) s += __shfl_xor(s, k);
            const float c = p * __builtin_amdgcn_rcpf(s);

#pragma unroll
            for (int e = 0; e < 8; ++e) Sacc[bb][e] = fmaf(c, uh[bb][e], Sacc[bb][e]);
        }

        // commit next x into the other buffer (wave-private; no barrier)
        if (ii + 1 < CH8)
            Xw[wv][(ii + 1) & 1][(lane & 7) * 8 + (lane >> 3)] = xnext;
    }

#pragma unroll
    for (int bb = 0; bb < 8; ++bb) {
        float* pp = partial + (size_t)chunk * BJE
                  + ((size_t)((bw0 + bb) * J_DIM + jj)) * E_DIM + eh * 8;
        *(float4*)pp       = make_float4(Sacc[bb][0], Sacc[bb][1], Sacc[bb][2], Sacc[bb][3]);
        *(float4*)(pp + 4) = make_float4(Sacc[bb][4], Sacc[bb][5], Sacc[bb][6], Sacc[bb][7]);
    }
}

// Sum partials over chunks (8 independent accumulators), then squash.
__global__ __launch_bounds__(256) void reduce_squash(
    const float* __restrict__ partial, float* __restrict__ Vacc,
    float* __restrict__ out, const int nc, const int final_it)
{
    const int t = blockIdx.x * blockDim.x + threadIdx.x;  // 0..BJE-1
    float a0=0.f,a1=0.f,a2=0.f,a3=0.f,a4=0.f,a5=0.f,a6=0.f,a7=0.f;
    for (int c = 0; c < nc; c += 8) {
        a0 += partial[(size_t)(c+0) * BJE + t];
        a1 += partial[(size_t)(c+1) * BJE + t];
        a2 += partial[(size_t)(c+2) * BJE + t];
        a3 += partial[(size_t)(c+3) * BJE + t];
        a4 += partial[(size_t)(c+4) * BJE + t];
        a5 += partial[(size_t)(c+5) * BJE + t];
        a6 += partial[(size_t)(c+6) * BJE + t];
        a7 += partial[(size_t)(c+7) * BJE + t];
    }
    const float acc = ((a0+a1)+(a2+a3)) + ((a4+a5)+(a6+a7));

    float s2 = acc * acc;
#pragma unroll
    for (int k = 8; k >= 1; k >>= 1) s2 += __shfl_xor(s2, k);  // reduce over e
    const float scale = s2 / (1.f + s2) * rsqrtf(s2 + 1e-7f);
    const float v = scale * acc;
    if (final_it) out[t] = v;
    else Vacc[t] += v;
}

extern "C" void kernel_launch(void* const* d_in, const int* in_sizes, int n_in,
                              void* d_out, int out_size, void* d_ws, size_t ws_size,
                              hipStream_t stream) {
    const float* x  = (const float*)d_in[0];   // [64,2304,8]
    const float* W  = (const float*)d_in[1];   // [2304,32,8,16]
    const float* b0 = (const float*)d_in[2];   // [2304,32]
    float* out = (float*)d_out;                // [64,32,16]

    // ws layout: partial[256][BJE] (33.5 MB) + Vacc[BJE] (128 KB); ws proven
    // >= 33.7 MB in rounds 3-7.
    float* partial = (float*)d_ws;
    float* Vacc    = partial + (size_t)NC8 * BJE;

    hipMemsetAsync(Vacc, 0, BJE * sizeof(float), stream);

    for (int it = 0; it < 3; ++it) {
        caps_pass_v8<<<NC8, 512, 0, stream>>>(x, W, b0, Vacc, partial);
        reduce_squash<<<BJE / 256, 256, 0, stream>>>(partial, Vacc, out, NC8, it == 2 ? 1 : 0);
    }
}

// Round 9
// 257.588 us; speedup vs baseline: 1.3254x; 1.3254x over previous
//
#include <hip/hip_runtime.h>

#define I_DIM 2304
#define J_DIM 32
#define D_IN  8
#define E_DIM 16
#define B_DIM 64
#define BJE   (B_DIM * J_DIM * E_DIM)  // 32768
#define NC9   256
#define CH9   (I_DIM / NC9)            // 9
#define TILEW 4096                     // floats per 16KB W tile

typedef const __attribute__((address_space(1))) char* gcp_t;
typedef __attribute__((address_space(3)))       char* lcp_t;

// grid = 256 (one block per i-chunk ~= one per CU), 1024 threads = 16 waves.
// Prologue: DMA ALL 9 W tiles (144 KB) to LDS once (source-XOR-swizzled,
// linear dest), stage b0 + x(i0); ONE barrier; then the pass is barrier-free.
// Wave wv owns b = wv*4 + bb (16 waves x 4 = 64 b). Lane: jj = j, eh = e-half;
// per-lane tile 4b x 8e (v7's proven 84-VGPR footprint, no spill).
// x: 1 dword/lane/iter prefetch -> wave-private LDS slot (no barrier needed).
__global__ __launch_bounds__(1024, 1) void caps_pass_v9(
    const float* __restrict__ x,    // [B, I, 8]
    const float* __restrict__ W,    // [I, J, 8, 16]
    const float* __restrict__ b0,   // [I, J]
    const float* __restrict__ Vacc, // [B, J, 16]
    float* __restrict__ partial)    // [NC9, B, J, 16]
{
    const int tid   = threadIdx.x;
    const int wv    = __builtin_amdgcn_readfirstlane(tid >> 6);  // 0..15 (SGPR)
    const int lane  = tid & 63;
    const int jj    = lane & 31;
    const int eh    = lane >> 5;
    const int km    = jj & 15;
    const int chunk = blockIdx.x;        // 0..255
    const int i0    = chunk * CH9;
    const int bw0   = wv * 4;            // wave's 4 b's (also global b base)

    __shared__ float Ws[CH9 * TILEW];    // 147,456 B (linear; swizzled source)
    __shared__ float Xw[16][2][32];      // 4,096 B  [wave][buf][d*4+bl]
    __shared__ float B0s[CH9 * J_DIM];   // 1,152 B

    // ---- prologue: DMA all 9 W tiles (each thread 1 16B-unit per tile) ----
    {
        const int g    = tid;                                       // unit 0..1023
        const int srcu = (g & ~31) | ((g & 31) ^ ((g >> 5) & 15));  // swizzled src
        for (int t = 0; t < CH9; ++t) {
            const char* wt = (const char*)(W + (size_t)(i0 + t) * TILEW);
            __builtin_amdgcn_global_load_lds(
                (gcp_t)(wt + (size_t)srcu * 16),
                (lcp_t)((char*)&Ws[t * TILEW + g * 4]),
                16, 0, 0);
        }
    }
    if (tid < CH9 * J_DIM) B0s[tid] = b0[i0 * J_DIM + tid];
    {
        // x(i0): per wave 4 b x 8 d = 32 values; lanes 32..63 duplicate (benign)
        const int bl = (lane & 31) >> 3, d = lane & 7;
        Xw[wv][0][d * 4 + bl] = x[((size_t)(bw0 + bl) * I_DIM + i0) * D_IN + d];
    }

    float vacc[4][8];
#pragma unroll
    for (int bb = 0; bb < 4; ++bb) {
        const float* vp = Vacc + ((size_t)((bw0 + bb) * J_DIM + jj)) * E_DIM + eh * 8;
        const float4 v0 = *(const float4*)vp;
        const float4 v1 = *(const float4*)(vp + 4);
        vacc[bb][0]=v0.x; vacc[bb][1]=v0.y; vacc[bb][2]=v0.z; vacc[bb][3]=v0.w;
        vacc[bb][4]=v1.x; vacc[bb][5]=v1.y; vacc[bb][6]=v1.z; vacc[bb][7]=v1.w;
    }

    float Sacc[4][8];
#pragma unroll
    for (int bb = 0; bb < 4; ++bb)
#pragma unroll
        for (int e = 0; e < 8; ++e) Sacc[bb][e] = 0.f;

    __syncthreads();   // ONLY barrier: drains W-DMA + b0 + x(i0)

    for (int ii = 0; ii < CH9; ++ii) {
        // prefetch next x (1 dword/lane; lanes 32-63 duplicate) — commit at end
        float xnext = 0.f;
        if (ii + 1 < CH9)
            xnext = x[((size_t)(bw0 + ((lane & 31) >> 3)) * I_DIM + (i0 + ii + 1)) * D_IN + (lane & 7)];

        const float* wb = &Ws[ii * TILEW];
        const float* xr = &Xw[wv][ii & 1][0];

        float uh[4][8];
#pragma unroll
        for (int bb = 0; bb < 4; ++bb)
#pragma unroll
            for (int e = 0; e < 8; ++e) uh[bb][e] = 0.f;

#pragma unroll
        for (int d = 0; d < D_IN; ++d) {
            const int u0 = (d << 2) | (eh << 1);
            const float4 wlo = *(const float4*)&wb[jj * 128 + (((u0    ) ^ km) << 2)];
            const float4 whi = *(const float4*)&wb[jj * 128 + (((u0 | 1) ^ km) << 2)];
            const float4 xa  = *(const float4*)&xr[d * 4];   // uniform broadcast
            const float xq[4] = {xa.x, xa.y, xa.z, xa.w};
#pragma unroll
            for (int bb = 0; bb < 4; ++bb) {
                const float xv = xq[bb];
                uh[bb][0] = fmaf(xv, wlo.x, uh[bb][0]);
                uh[bb][1] = fmaf(xv, wlo.y, uh[bb][1]);
                uh[bb][2] = fmaf(xv, wlo.z, uh[bb][2]);
                uh[bb][3] = fmaf(xv, wlo.w, uh[bb][3]);
                uh[bb][4] = fmaf(xv, whi.x, uh[bb][4]);
                uh[bb][5] = fmaf(xv, whi.y, uh[bb][5]);
                uh[bb][6] = fmaf(xv, whi.z, uh[bb][6]);
                uh[bb][7] = fmaf(xv, whi.w, uh[bb][7]);
            }
        }

        const float b0v = B0s[ii * J_DIM + jj];
#pragma unroll
        for (int bb = 0; bb < 4; ++bb) {
            float l0 = 0.f, l1 = 0.f;
#pragma unroll
            for (int e = 0; e < 8; e += 2) {
                l0 = fmaf(vacc[bb][e],     uh[bb][e],     l0);
                l1 = fmaf(vacc[bb][e + 1], uh[bb][e + 1], l1);
            }
            float lg = l0 + l1;
            lg += __shfl_xor(lg, 32);              // other e-half
            const float l = b0v + lg;

            // softmax over jj (no max-sub: |l| fp32-safe; exact-math equal)
            const float p = __expf(l);
            float s = p;
#pragma unroll
            for (int k = 16; k >= 1; k >>= 1) s += __shfl_xor(s, k);
            const float c = p * __builtin_amdgcn_rcpf(s);

#pragma unroll
            for (int e = 0; e < 8; ++e) Sacc[bb][e] = fmaf(c, uh[bb][e], Sacc[bb][e]);
        }

        // commit next x into the other wave-private buffer (no barrier)
        if (ii + 1 < CH9)
            Xw[wv][(ii + 1) & 1][(lane & 7) * 4 + ((lane & 31) >> 3)] = xnext;
    }

#pragma unroll
    for (int bb = 0; bb < 4; ++bb) {
        float* pp = partial + (size_t)chunk * BJE
                  + ((size_t)((bw0 + bb) * J_DIM + jj)) * E_DIM + eh * 8;
        *(float4*)pp       = make_float4(Sacc[bb][0], Sacc[bb][1], Sacc[bb][2], Sacc[bb][3]);
        *(float4*)(pp + 4) = make_float4(Sacc[bb][4], Sacc[bb][5], Sacc[bb][6], Sacc[bb][7]);
    }
}

// Sum partials over chunks (8 independent accumulators), then squash.
__global__ __launch_bounds__(256) void reduce_squash(
    const float* __restrict__ partial, float* __restrict__ Vacc,
    float* __restrict__ out, const int nc, const int final_it)
{
    const int t = blockIdx.x * blockDim.x + threadIdx.x;  // 0..BJE-1
    float a0=0.f,a1=0.f,a2=0.f,a3=0.f,a4=0.f,a5=0.f,a6=0.f,a7=0.f;
    for (int c = 0; c < nc; c += 8) {
        a0 += partial[(size_t)(c+0) * BJE + t];
        a1 += partial[(size_t)(c+1) * BJE + t];
        a2 += partial[(size_t)(c+2) * BJE + t];
        a3 += partial[(size_t)(c+3) * BJE + t];
        a4 += partial[(size_t)(c+4) * BJE + t];
        a5 += partial[(size_t)(c+5) * BJE + t];
        a6 += partial[(size_t)(c+6) * BJE + t];
        a7 += partial[(size_t)(c+7) * BJE + t];
    }
    const float acc = ((a0+a1)+(a2+a3)) + ((a4+a5)+(a6+a7));

    float s2 = acc * acc;
#pragma unroll
    for (int k = 8; k >= 1; k >>= 1) s2 += __shfl_xor(s2, k);  // reduce over e
    const float scale = s2 / (1.f + s2) * rsqrtf(s2 + 1e-7f);
    const float v = scale * acc;
    if (final_it) out[t] = v;
    else Vacc[t] += v;
}

extern "C" void kernel_launch(void* const* d_in, const int* in_sizes, int n_in,
                              void* d_out, int out_size, void* d_ws, size_t ws_size,
                              hipStream_t stream) {
    const float* x  = (const float*)d_in[0];   // [64,2304,8]
    const float* W  = (const float*)d_in[1];   // [2304,32,8,16]
    const float* b0 = (const float*)d_in[2];   // [2304,32]
    float* out = (float*)d_out;                // [64,32,16]

    // ws layout: partial[256][BJE] (33.5 MB) + Vacc[BJE] (128 KB); ws proven
    // >= 33.7 MB in rounds 3-8.
    float* partial = (float*)d_ws;
    float* Vacc    = partial + (size_t)NC9 * BJE;

    hipMemsetAsync(Vacc, 0, BJE * sizeof(float), stream);

    for (int it = 0; it < 3; ++it) {
        caps_pass_v9<<<NC9, 1024, 0, stream>>>(x, W, b0, Vacc, partial);
        reduce_squash<<<BJE / 256, 256, 0, stream>>>(partial, Vacc, out, NC9, it == 2 ? 1 : 0);
    }
}